// Round 1
// baseline (734.268 us; speedup 1.0000x reference)
//
#include <hip/hip_runtime.h>
#include <stdint.h>

#define B_     64
#define N_     197
#define DIM_   768
#define HEADS_ 12
#define HD_    64
#define M_     (B_*N_)      // 12608
#define K3_    (3*DIM_)     // 2304
#define NN2_   (N_*N_)      // 38809
#define SCALE_ 0.125f

typedef _Float16 f16x8 __attribute__((ext_vector_type(8)));
typedef _Float16 f16x4 __attribute__((ext_vector_type(4)));
typedef float    f32x4 __attribute__((ext_vector_type(4)));

__device__ __forceinline__ void gload_lds16(const void* g, void* l) {
    __builtin_amdgcn_global_load_lds(
        (const __attribute__((address_space(1))) uint32_t*)g,
        (__attribute__((address_space(3))) uint32_t*)l, 16, 0, 0);
}

// ---------------- f32 -> f16 convert ----------------
__global__ __launch_bounds__(256) void cvt_f32_f16(const float* __restrict__ s,
                                                   _Float16* __restrict__ d, int n4) {
    int i = blockIdx.x * 256 + threadIdx.x;
    if (i < n4) {
        const float4 v = *(const float4*)(s + (size_t)i * 4);
        f16x4 o;
        o[0] = (_Float16)v.x; o[1] = (_Float16)v.y;
        o[2] = (_Float16)v.z; o[3] = (_Float16)v.w;
        *(f16x4*)(d + (size_t)i * 4) = o;
    }
}

// ---------------- rel-pos bias gather: biasf[h][i][j] ----------------
__global__ __launch_bounds__(256) void bias_pre(const int* __restrict__ rel_index,
                                                const float* __restrict__ rel_table,
                                                float* __restrict__ biasf) {
    int t = blockIdx.x * 256 + threadIdx.x;
    if (t < HEADS_ * NN2_) {
        int h = t / NN2_, ij = t - h * NN2_;
        biasf[t] = rel_table[rel_index[ij] * HEADS_ + h];
    }
}

// ---------------- MFMA GEMM: C[M x Nout] = A[M x K] * Bw[Nout x K]^T + bias ----------------
// mode 0: out f16 (qkv buffer, stride K3_), bitfit q/v bias
// mode 1: out f32 (d_out, stride DIM_), proj bias
__global__ __launch_bounds__(256) void gemm_bt(
    const _Float16* __restrict__ A, const _Float16* __restrict__ Bw,
    int M, int K, int mode,
    const float* __restrict__ qb, const float* __restrict__ vb,
    const float* __restrict__ pb, const int* __restrict__ b_idx,
    _Float16* __restrict__ out_h, float* __restrict__ out_f)
{
    __shared__ __align__(16) _Float16 As[128 * 32];
    __shared__ __align__(16) _Float16 Bs[128 * 32];
    const int tid = threadIdx.x;
    const int lane = tid & 63;
    const int w = tid >> 6;
    const int m0 = blockIdx.y * 128, n0 = blockIdx.x * 128;
    const int wm = (w >> 1) * 64, wn = (w & 1) * 64;
    const int fr = lane & 15, fk = (lane >> 4) * 8;

    f32x4 acc[4][4];
    #pragma unroll
    for (int i = 0; i < 4; ++i)
        #pragma unroll
        for (int j = 0; j < 4; ++j)
            acc[i][j] = (f32x4)0.f;

    // staging chunk assignment: chunk c -> row c>>2, k-offset (c&3)*8 (16B each)
    const int c0 = tid, c1 = tid + 256;
    const int ar0 = c0 >> 2, ak0 = (c0 & 3) * 8;
    const int ar1 = c1 >> 2, ak1 = (c1 & 3) * 8;
    int gra0 = m0 + ar0; if (gra0 >= M) gra0 = M - 1;
    int gra1 = m0 + ar1; if (gra1 >= M) gra1 = M - 1;

    for (int k0 = 0; k0 < K; k0 += 32) {
        __syncthreads();
        gload_lds16(A + (size_t)gra0 * K + k0 + ak0, As + c0 * 8);
        gload_lds16(A + (size_t)gra1 * K + k0 + ak1, As + c1 * 8);
        gload_lds16(Bw + (size_t)(n0 + ar0) * K + k0 + ak0, Bs + c0 * 8);
        gload_lds16(Bw + (size_t)(n0 + ar1) * K + k0 + ak1, Bs + c1 * 8);
        asm volatile("s_waitcnt vmcnt(0)" ::: "memory");
        __syncthreads();

        f16x8 a[4], b[4];
        #pragma unroll
        for (int i = 0; i < 4; ++i)
            a[i] = *(const f16x8*)&As[(wm + i * 16 + fr) * 32 + fk];
        #pragma unroll
        for (int j = 0; j < 4; ++j)
            b[j] = *(const f16x8*)&Bs[(wn + j * 16 + fr) * 32 + fk];
        #pragma unroll
        for (int i = 0; i < 4; ++i)
            #pragma unroll
            for (int j = 0; j < 4; ++j)
                acc[i][j] = __builtin_amdgcn_mfma_f32_16x16x32_f16(a[i], b[j], acc[i][j], 0, 0, 0);
    }

    // epilogue: C/D layout: col = lane&15, row = (lane>>4)*4 + reg
    const int fq = lane >> 4;
    #pragma unroll
    for (int i = 0; i < 4; ++i) {
        #pragma unroll
        for (int rr = 0; rr < 4; ++rr) {
            const int row = m0 + wm + i * 16 + fq * 4 + rr;
            if (row < M) {
                const int bi = b_idx[row / N_];
                #pragma unroll
                for (int j = 0; j < 4; ++j) {
                    const int col = n0 + wn + j * 16 + fr;
                    float v = acc[i][j][rr];
                    if (mode == 0) {
                        float bias = 0.f;
                        if (col < DIM_) bias = qb[bi * DIM_ + col];
                        else if (col >= 2 * DIM_) bias = vb[bi * DIM_ + (col - 2 * DIM_)];
                        out_h[(size_t)row * K3_ + col] = (_Float16)(v + bias);
                    } else {
                        out_f[(size_t)row * DIM_ + col] = v + pb[bi * DIM_ + col];
                    }
                }
            }
        }
    }
}

// ---------------- attention (f32 VALU, per (b,h,32-row group)) ----------------
__global__ __launch_bounds__(256) void attn_f32(
    const _Float16* __restrict__ qkv, const float* __restrict__ biasf,
    _Float16* __restrict__ ctx)
{
    __shared__ float q_lds[32][64];     // scaled q rows
    __shared__ float KT[64 * 68];       // K tile [j][d] (scores) / V^T tile [d][j] (out), stride 68
    __shared__ float p_lds[32][256];    // scores -> probabilities

    const int b = blockIdx.z, h = blockIdx.y, rg = blockIdx.x;
    const int r0 = rg * 32;
    const int nr = min(32, N_ - r0);
    const int tid = threadIdx.x, lane = tid & 63, w = tid >> 6;
    const size_t base = (size_t)b * N_ * K3_;

    // stage q (pre-scaled)
    for (int idx = tid; idx < 32 * 64; idx += 256) {
        int row = idx >> 6, d = idx & 63;
        int n = r0 + row; if (n > N_ - 1) n = N_ - 1;
        q_lds[row][d] = (float)qkv[base + (size_t)n * K3_ + h * HD_ + d] * SCALE_;
    }

    // ---- scores: p_lds[row][j] = q.k + bias (raw) ----
    for (int t = 0; t < 4; ++t) {
        __syncthreads();
        for (int idx = tid; idx < 64 * 64; idx += 256) {
            int jj = idx >> 6, d = idx & 63;
            int j = t * 64 + jj; if (j > N_ - 1) j = N_ - 1;
            KT[jj * 68 + d] = (float)qkv[base + (size_t)j * K3_ + DIM_ + h * HD_ + d];
        }
        __syncthreads();
        const int jcol = t * 64 + lane;
        for (int rr = 0; rr < 8; ++rr) {
            const int row = w * 8 + rr;
            if (row < nr) {
                f32x4 s4 = (f32x4)0.f;
                #pragma unroll
                for (int d4 = 0; d4 < 16; ++d4) {
                    f32x4 kv = *(const f32x4*)&KT[lane * 68 + d4 * 4];
                    f32x4 qv = *(const f32x4*)&q_lds[row][d4 * 4];
                    s4 += qv * kv;
                }
                float s = s4.x + s4.y + s4.z + s4.w;
                if (jcol < N_) s += biasf[h * NN2_ + (r0 + row) * N_ + jcol];
                else s = -1e30f;
                p_lds[row][t * 64 + lane] = s;
            }
        }
    }

    // ---- softmax (per wave: its own 8 rows; 64-lane shfl reduce) ----
    for (int rr = 0; rr < 8; ++rr) {
        const int row = w * 8 + rr;
        if (row < nr) {
            float x0 = p_lds[row][lane];
            float x1 = p_lds[row][64 + lane];
            float x2 = p_lds[row][128 + lane];
            float x3 = p_lds[row][192 + lane];
            float m = fmaxf(fmaxf(x0, x1), fmaxf(x2, x3));
            #pragma unroll
            for (int off = 32; off > 0; off >>= 1) m = fmaxf(m, __shfl_xor(m, off));
            float e0 = __expf(x0 - m), e1 = __expf(x1 - m);
            float e2 = __expf(x2 - m), e3 = __expf(x3 - m);
            float ssum = e0 + e1 + e2 + e3;
            #pragma unroll
            for (int off = 32; off > 0; off >>= 1) ssum += __shfl_xor(ssum, off);
            float inv = 1.f / ssum;
            p_lds[row][lane]       = e0 * inv;
            p_lds[row][64 + lane]  = e1 * inv;
            p_lds[row][128 + lane] = e2 * inv;
            p_lds[row][192 + lane] = e3 * inv;
        }
    }

    // ---- out = P @ V ----
    f32x4 acc4[8];
    #pragma unroll
    for (int rr = 0; rr < 8; ++rr) acc4[rr] = (f32x4)0.f;
    for (int t = 0; t < 4; ++t) {
        __syncthreads();
        for (int idx = tid; idx < 64 * 64; idx += 256) {
            int jj = idx >> 6, d = idx & 63;
            int j = t * 64 + jj;
            float v = 0.f;
            if (j < N_) v = (float)qkv[base + (size_t)j * K3_ + 2 * DIM_ + h * HD_ + d];
            KT[d * 68 + jj] = v;   // V^T[d][jj], zero-padded past N
        }
        __syncthreads();
        for (int rr = 0; rr < 8; ++rr) {
            const int row = w * 8 + rr;
            if (row < nr) {
                f32x4 a = acc4[rr];
                #pragma unroll
                for (int jj4 = 0; jj4 < 16; ++jj4) {
                    f32x4 pv = *(const f32x4*)&p_lds[row][t * 64 + jj4 * 4];
                    f32x4 vv = *(const f32x4*)&KT[lane * 68 + jj4 * 4];
                    a += pv * vv;
                }
                acc4[rr] = a;
            }
        }
    }
    #pragma unroll
    for (int rr = 0; rr < 8; ++rr) {
        const int row = w * 8 + rr;
        if (row < nr) {
            float o = acc4[rr].x + acc4[rr].y + acc4[rr].z + acc4[rr].w;
            ctx[((size_t)b * N_ + (r0 + row)) * DIM_ + h * HD_ + lane] = (_Float16)o;
        }
    }
}

// ---------------- launcher ----------------
extern "C" void kernel_launch(void* const* d_in, const int* in_sizes, int n_in,
                              void* d_out, int out_size, void* d_ws, size_t ws_size,
                              hipStream_t stream) {
    const float* x     = (const float*)d_in[0];
    const float* wqkv  = (const float*)d_in[1];
    const float* qb    = (const float*)d_in[2];
    const float* vb    = (const float*)d_in[3];
    const float* rt    = (const float*)d_in[4];
    const float* wproj = (const float*)d_in[5];
    const float* pbias = (const float*)d_in[6];
    const int* b_idx   = (const int*)d_in[7];
    const int* rel_idx = (const int*)d_in[8];
    float* out = (float*)d_out;

    char* ws = (char*)d_ws;
    size_t off = 0;
    auto alloc = [&](size_t bytes) -> void* {
        void* p = ws + off; off += (bytes + 255) & ~(size_t)255; return p;
    };
    _Float16* xb   = (_Float16*)alloc((size_t)M_ * DIM_ * 2);
    _Float16* wqh  = (_Float16*)alloc((size_t)K3_ * DIM_ * 2);
    _Float16* wph  = (_Float16*)alloc((size_t)DIM_ * DIM_ * 2);
    _Float16* qkvh = (_Float16*)alloc((size_t)M_ * K3_ * 2);
    _Float16* ctx  = (_Float16*)alloc((size_t)M_ * DIM_ * 2);
    float*    biasf = (float*)alloc((size_t)HEADS_ * NN2_ * 4);

    cvt_f32_f16<<<dim3((M_ * DIM_ / 4 + 255) / 256), 256, 0, stream>>>(x, xb, M_ * DIM_ / 4);
    cvt_f32_f16<<<dim3((K3_ * DIM_ / 4 + 255) / 256), 256, 0, stream>>>(wqkv, wqh, K3_ * DIM_ / 4);
    cvt_f32_f16<<<dim3((DIM_ * DIM_ / 4 + 255) / 256), 256, 0, stream>>>(wproj, wph, DIM_ * DIM_ / 4);
    bias_pre<<<dim3((HEADS_ * NN2_ + 255) / 256), 256, 0, stream>>>(rel_idx, rt, biasf);

    gemm_bt<<<dim3(K3_ / 128, (M_ + 127) / 128), 256, 0, stream>>>(
        xb, wqh, M_, DIM_, 0, qb, vb, nullptr, b_idx, qkvh, nullptr);

    attn_f32<<<dim3(7, HEADS_, B_), 256, 0, stream>>>(qkvh, biasf, ctx);

    gemm_bt<<<dim3(DIM_ / 128, (M_ + 127) / 128), 256, 0, stream>>>(
        ctx, wph, M_, DIM_, 1, nullptr, nullptr, pbias, b_idx, nullptr, out);
}

// Round 3
// 235.181 us; speedup vs baseline: 3.1221x; 3.1221x over previous
//
#include <hip/hip_runtime.h>
#include <stdint.h>

#define B_     64
#define N_     197
#define DIM_   768
#define HEADS_ 12
#define HD_    64
#define M_     (B_*N_)      // 12608
#define K3_    (3*DIM_)     // 2304
#define NP_    208          // padded N (13*16)
#define KSTR_  72           // K_lds row stride (f16)
#define VSTR_  232          // VT / P row stride (f16)
#define SCALE_ 0.125f

typedef _Float16 f16x8 __attribute__((ext_vector_type(8)));
typedef _Float16 f16x4 __attribute__((ext_vector_type(4)));
typedef _Float16 f16x2 __attribute__((ext_vector_type(2)));
typedef float    f32x4 __attribute__((ext_vector_type(4)));

__device__ __forceinline__ void gload_lds16(const void* g, void* l) {
    __builtin_amdgcn_global_load_lds(
        (const __attribute__((address_space(1))) uint32_t*)g,
        (__attribute__((address_space(3))) uint32_t*)l, 16, 0, 0);
}

// ---------------- f32 -> f16 convert ----------------
__global__ __launch_bounds__(256) void cvt_f32_f16(const float* __restrict__ s,
                                                   _Float16* __restrict__ d, int n4) {
    int i = blockIdx.x * 256 + threadIdx.x;
    if (i < n4) {
        const float4 v = *(const float4*)(s + (size_t)i * 4);
        f16x4 o;
        o[0] = (_Float16)v.x; o[1] = (_Float16)v.y;
        o[2] = (_Float16)v.z; o[3] = (_Float16)v.w;
        *(f16x4*)(d + (size_t)i * 4) = o;
    }
}

// ---------------- transposed rel-pos bias: biasT[h][k][q], padded 208x208 ----------------
__global__ __launch_bounds__(256) void biasT_pre(const int* __restrict__ rel_index,
                                                 const float* __restrict__ rel_table,
                                                 float* __restrict__ biasT) {
    int t = blockIdx.x * 256 + threadIdx.x;
    if (t < HEADS_ * NP_ * NP_) {
        int h = t / (NP_ * NP_), rem = t - h * (NP_ * NP_);
        int k = rem / NP_, q = rem - k * NP_;
        float v;
        if (k >= N_)      v = -1e30f;   // padded key -> exp()->0
        else if (q >= N_) v = 0.f;      // padded query -> finite, never stored
        else              v = rel_table[rel_index[q * N_ + k] * HEADS_ + h];
        biasT[t] = v;
    }
}

// ---------------- MFMA GEMM: C[M x Nout] = A[M x K] * Bw[Nout x K]^T + bias ----------------
__global__ __launch_bounds__(256) void gemm_bt(
    const _Float16* __restrict__ A, const _Float16* __restrict__ Bw,
    int M, int K, int mode,
    const float* __restrict__ qb, const float* __restrict__ vb,
    const float* __restrict__ pb, const int* __restrict__ b_idx,
    _Float16* __restrict__ out_h, float* __restrict__ out_f)
{
    __shared__ __align__(16) _Float16 As[128 * 32];
    __shared__ __align__(16) _Float16 Bs[128 * 32];
    const int tid = threadIdx.x;
    const int lane = tid & 63;
    const int w = tid >> 6;
    const int m0 = blockIdx.y * 128, n0 = blockIdx.x * 128;
    const int wm = (w >> 1) * 64, wn = (w & 1) * 64;
    const int fr = lane & 15, fk = (lane >> 4) * 8;

    f32x4 acc[4][4];
    #pragma unroll
    for (int i = 0; i < 4; ++i)
        #pragma unroll
        for (int j = 0; j < 4; ++j)
            acc[i][j] = (f32x4)0.f;

    const int c0 = tid, c1 = tid + 256;
    const int ar0 = c0 >> 2, ak0 = (c0 & 3) * 8;
    const int ar1 = c1 >> 2, ak1 = (c1 & 3) * 8;
    int gra0 = m0 + ar0; if (gra0 >= M) gra0 = M - 1;
    int gra1 = m0 + ar1; if (gra1 >= M) gra1 = M - 1;

    for (int k0 = 0; k0 < K; k0 += 32) {
        __syncthreads();
        gload_lds16(A + (size_t)gra0 * K + k0 + ak0, As + c0 * 8);
        gload_lds16(A + (size_t)gra1 * K + k0 + ak1, As + c1 * 8);
        gload_lds16(Bw + (size_t)(n0 + ar0) * K + k0 + ak0, Bs + c0 * 8);
        gload_lds16(Bw + (size_t)(n0 + ar1) * K + k0 + ak1, Bs + c1 * 8);
        asm volatile("s_waitcnt vmcnt(0)" ::: "memory");
        __syncthreads();

        f16x8 a[4], b[4];
        #pragma unroll
        for (int i = 0; i < 4; ++i)
            a[i] = *(const f16x8*)&As[(wm + i * 16 + fr) * 32 + fk];
        #pragma unroll
        for (int j = 0; j < 4; ++j)
            b[j] = *(const f16x8*)&Bs[(wn + j * 16 + fr) * 32 + fk];
        #pragma unroll
        for (int i = 0; i < 4; ++i)
            #pragma unroll
            for (int j = 0; j < 4; ++j)
                acc[i][j] = __builtin_amdgcn_mfma_f32_16x16x32_f16(a[i], b[j], acc[i][j], 0, 0, 0);
    }

    const int fq = lane >> 4;
    #pragma unroll
    for (int i = 0; i < 4; ++i) {
        #pragma unroll
        for (int rr = 0; rr < 4; ++rr) {
            const int row = m0 + wm + i * 16 + fq * 4 + rr;
            if (row < M) {
                const int bi = b_idx[row / N_];
                #pragma unroll
                for (int j = 0; j < 4; ++j) {
                    const int col = n0 + wn + j * 16 + fr;
                    float v = acc[i][j][rr];
                    if (mode == 0) {
                        float bias = 0.f;
                        if (col < DIM_) bias = qb[bi * DIM_ + col];
                        else if (col >= 2 * DIM_) bias = vb[bi * DIM_ + (col - 2 * DIM_)];
                        out_h[(size_t)row * K3_ + col] = (_Float16)(v + bias);
                    } else {
                        out_f[(size_t)row * DIM_ + col] = v + pb[bi * DIM_ + col];
                    }
                }
            }
        }
    }
}

// ---------------- MFMA attention: one block per (b, h, 64-row q-tile) ----------------
__global__ __launch_bounds__(256) void attn_mfma(
    const _Float16* __restrict__ qkv, const float* __restrict__ biasT,
    _Float16* __restrict__ ctx)
{
    __shared__ __align__(16) _Float16 KP[NP_ * KSTR_];   // K tile, reused as P tile
    __shared__ __align__(16) _Float16 VT[HD_ * VSTR_];   // V^T tile

    const int b = blockIdx.z, h = blockIdx.y, rt = blockIdx.x;
    const int r0 = rt * 64;
    const int tid = threadIdx.x, lane = tid & 63, w = tid >> 6;
    const int fr = lane & 15, g = lane >> 4;

    const size_t baseQ = (size_t)b * N_ * K3_ + h * HD_;
    const size_t baseK = baseQ + DIM_;
    const size_t baseV = baseQ + 2 * DIM_;

    // ---- stage K rows [208 x 64] -> KP (stride 72), clamp-dup padded rows ----
    for (int idx = tid; idx < NP_ * 8; idx += 256) {
        int row = idx % NP_, dc = idx / NP_;
        int gk = min(row, N_ - 1);
        f16x8 v = *(const f16x8*)(qkv + baseK + (size_t)gk * K3_ + dc * 8);
        *(f16x8*)(KP + row * KSTR_ + dc * 8) = v;
    }
    // ---- stage V^T [64 d x 224 j] -> VT (stride 232), ZERO-fill j >= N_ ----
    for (int idx = tid; idx < 112 * 8; idx += 256) {
        int jp = idx % 112, dc = idx / 112;
        int j0 = 2 * jp, j1 = 2 * jp + 1;
        f16x8 zz = {};
        f16x8 v0 = (j0 < N_) ? *(const f16x8*)(qkv + baseV + (size_t)j0 * K3_ + dc * 8) : zz;
        f16x8 v1 = (j1 < N_) ? *(const f16x8*)(qkv + baseV + (size_t)j1 * K3_ + dc * 8) : zz;
        #pragma unroll
        for (int e = 0; e < 8; ++e) {
            f16x2 p; p[0] = v0[e]; p[1] = v1[e];
            *(f16x2*)(VT + (dc * 8 + e) * VSTR_ + 2 * jp) = p;
        }
    }
    // ---- Q fragments (B-operand): wave w owns q rows r0+w*16..+15 ----
    const int qrow = min(r0 + w * 16 + fr, N_ - 1);
    f16x8 qf[2];
    qf[0] = *(const f16x8*)(qkv + baseQ + (size_t)qrow * K3_ + g * 8);
    qf[1] = *(const f16x8*)(qkv + baseQ + (size_t)qrow * K3_ + 32 + g * 8);

    __syncthreads();

    // ---- S^T[k][q] = K.Q^T ----
    f32x4 acc[13];
    #pragma unroll
    for (int jf = 0; jf < 13; ++jf) acc[jf] = (f32x4)0.f;
    #pragma unroll
    for (int jf = 0; jf < 13; ++jf) {
        #pragma unroll
        for (int kk = 0; kk < 2; ++kk) {
            f16x8 a = *(const f16x8*)&KP[(jf * 16 + fr) * KSTR_ + kk * 32 + g * 8];
            acc[jf] = __builtin_amdgcn_mfma_f32_16x16x32_f16(a, qf[kk], acc[jf], 0, 0, 0);
        }
    }

    // ---- softmax: lane holds S^T[k = jf*16+g*4+r][q = r0+w*16+fr] ----
    const int qb_ = min(r0 + w * 16 + fr, NP_ - 1);
    const float* bp = biasT + (size_t)h * NP_ * NP_ + qb_;
    float mx = -3e38f;
    #pragma unroll
    for (int jf = 0; jf < 13; ++jf) {
        #pragma unroll
        for (int r = 0; r < 4; ++r) {
            int k = jf * 16 + g * 4 + r;
            float s = acc[jf][r] * SCALE_ + bp[(size_t)k * NP_];
            acc[jf][r] = s;
            mx = fmaxf(mx, s);
        }
    }
    mx = fmaxf(mx, __shfl_xor(mx, 16));
    mx = fmaxf(mx, __shfl_xor(mx, 32));
    float sum = 0.f;
    #pragma unroll
    for (int jf = 0; jf < 13; ++jf) {
        #pragma unroll
        for (int r = 0; r < 4; ++r) {
            float e = __expf(acc[jf][r] - mx);
            acc[jf][r] = e;
            sum += e;
        }
    }
    sum += __shfl_xor(sum, 16);
    sum += __shfl_xor(sum, 32);
    const float inv = 1.f / sum;

    __syncthreads();   // everyone done reading K before P overwrites it

    // ---- P[q][k] f16 -> KP region (stride 232) ----
    #pragma unroll
    for (int jf = 0; jf < 13; ++jf) {
        f16x4 p;
        #pragma unroll
        for (int r = 0; r < 4; ++r) p[r] = (_Float16)(acc[jf][r] * inv);
        *(f16x4*)(KP + (size_t)(w * 16 + fr) * VSTR_ + jf * 16 + g * 4) = p;
    }
    {   // zero tail cols 208..223 so PV's 7th k-step reads zeros
        f16x4 z = {};
        *(f16x4*)(KP + (size_t)(w * 16 + fr) * VSTR_ + NP_ + g * 4) = z;
    }
    __syncthreads();

    // ---- out[q][d] = P . V ----
    f32x4 oacc[4];
    #pragma unroll
    for (int dj = 0; dj < 4; ++dj) oacc[dj] = (f32x4)0.f;
    #pragma unroll
    for (int ks = 0; ks < 7; ++ks) {
        f16x8 a = *(const f16x8*)&KP[(size_t)(w * 16 + fr) * VSTR_ + ks * 32 + g * 8];
        #pragma unroll
        for (int dj = 0; dj < 4; ++dj) {
            f16x8 bf = *(const f16x8*)&VT[(dj * 16 + fr) * VSTR_ + ks * 32 + g * 8];
            oacc[dj] = __builtin_amdgcn_mfma_f32_16x16x32_f16(a, bf, oacc[dj], 0, 0, 0);
        }
    }
    #pragma unroll
    for (int dj = 0; dj < 4; ++dj) {
        #pragma unroll
        for (int r = 0; r < 4; ++r) {
            const int q = r0 + w * 16 + g * 4 + r;
            if (q < N_)
                ctx[((size_t)b * N_ + q) * DIM_ + h * HD_ + dj * 16 + fr] =
                    (_Float16)oacc[dj][r];
        }
    }
}

// ---------------- launcher ----------------
extern "C" void kernel_launch(void* const* d_in, const int* in_sizes, int n_in,
                              void* d_out, int out_size, void* d_ws, size_t ws_size,
                              hipStream_t stream) {
    const float* x     = (const float*)d_in[0];
    const float* wqkv  = (const float*)d_in[1];
    const float* qb    = (const float*)d_in[2];
    const float* vb    = (const float*)d_in[3];
    const float* rt    = (const float*)d_in[4];
    const float* wproj = (const float*)d_in[5];
    const float* pbias = (const float*)d_in[6];
    const int* b_idx   = (const int*)d_in[7];
    const int* rel_idx = (const int*)d_in[8];
    float* out = (float*)d_out;

    char* ws = (char*)d_ws;
    size_t off = 0;
    auto alloc = [&](size_t bytes) -> void* {
        void* p = ws + off; off += (bytes + 255) & ~(size_t)255; return p;
    };
    _Float16* xb    = (_Float16*)alloc((size_t)M_ * DIM_ * 2);
    _Float16* wqh   = (_Float16*)alloc((size_t)K3_ * DIM_ * 2);
    _Float16* wph   = (_Float16*)alloc((size_t)DIM_ * DIM_ * 2);
    _Float16* qkvh  = (_Float16*)alloc((size_t)M_ * K3_ * 2);
    _Float16* ctx   = (_Float16*)alloc((size_t)M_ * DIM_ * 2);
    float*    biasT = (float*)alloc((size_t)HEADS_ * NP_ * NP_ * 4);

    cvt_f32_f16<<<dim3((M_ * DIM_ / 4 + 255) / 256), 256, 0, stream>>>(x, xb, M_ * DIM_ / 4);
    cvt_f32_f16<<<dim3((K3_ * DIM_ / 4 + 255) / 256), 256, 0, stream>>>(wqkv, wqh, K3_ * DIM_ / 4);
    cvt_f32_f16<<<dim3((DIM_ * DIM_ / 4 + 255) / 256), 256, 0, stream>>>(wproj, wph, DIM_ * DIM_ / 4);
    biasT_pre<<<dim3((HEADS_ * NP_ * NP_ + 255) / 256), 256, 0, stream>>>(rel_idx, rt, biasT);

    gemm_bt<<<dim3(K3_ / 128, (M_ + 127) / 128), 256, 0, stream>>>(
        xb, wqh, M_, DIM_, 0, qb, vb, nullptr, b_idx, qkvh, nullptr);

    attn_mfma<<<dim3(4, HEADS_, B_), 256, 0, stream>>>(qkvh, biasT, ctx);

    gemm_bt<<<dim3(DIM_ / 128, (M_ + 127) / 128), 256, 0, stream>>>(
        ctx, wph, M_, DIM_, 1, nullptr, nullptr, pbias, b_idx, nullptr, out);
}